// Round 1
// baseline (4863.573 us; speedup 1.0000x reference)
//
#include <hip/hip_runtime.h>
#include <hip/hip_fp16.h>

#define NH 4
#define HD 64
#define MF 266
#define NBCTX 128
#define DN 0.35355339059327373f
#define RATIO 0.06131393394849658f
#define EPSRF 1e-4f

typedef unsigned short u16;
typedef unsigned int u32;

__device__ __forceinline__ float bf2f(u16 u){ return __uint_as_float(((u32)u)<<16); }
__device__ __forceinline__ u16 f2bf(float f){ u32 u = __float_as_uint(f); u += 0x7FFFu + ((u>>16)&1u); return (u16)(u>>16); }
__device__ __forceinline__ float eluf(float x){ return x>0.f ? x : (expf(x)-1.f); }

// ---------------- K1: fused projection GEMM: [N,256] @ [256,1024]^T ----------------
// col 0..255->Q, 256..511->K, 512..767->V, 768..1023->gnn1. Q/K/V head-major bf16.
__global__ __launch_bounds__(256) void k_proj(
    const float* __restrict__ x,
    const float* __restrict__ qw, const float* __restrict__ kw,
    const float* __restrict__ vw, const float* __restrict__ lw,
    const float* __restrict__ qb, const float* __restrict__ kb,
    const float* __restrict__ vb, const float* __restrict__ lb,
    u16* __restrict__ Q, u16* __restrict__ K, u16* __restrict__ V,
    u16* __restrict__ G1, int n)
{
  __shared__ float As[16][68];
  __shared__ float Bs[16][68];
  const int tid = threadIdx.x;
  const int row0 = blockIdx.x*64;
  const int col0 = blockIdx.y*64;
  const int sel = col0>>8;
  const float* wsel = sel==0?qw : sel==1?kw : sel==2?vw : lw;
  const float* bsel = sel==0?qb : sel==1?kb : sel==2?vb : lb;
  u16* dsel = sel==0?Q : sel==1?K : sel==2?V : G1;
  const int tx = tid&15, ty = tid>>4;
  const int lr = tid>>2, lk = (tid&3)*4;
  float acc[4][4] = {};
  for (int kt=0; kt<16; ++kt){
    const int k0 = kt*16;
    float4 av = make_float4(0.f,0.f,0.f,0.f);
    if (row0+lr < n) av = *(const float4*)(x + (size_t)(row0+lr)*256 + k0 + lk);
    float4 bv = *(const float4*)(wsel + (size_t)((col0&255)+lr)*256 + k0 + lk);
    __syncthreads();
    As[lk+0][lr]=av.x; As[lk+1][lr]=av.y; As[lk+2][lr]=av.z; As[lk+3][lr]=av.w;
    Bs[lk+0][lr]=bv.x; Bs[lk+1][lr]=bv.y; Bs[lk+2][lr]=bv.z; Bs[lk+3][lr]=bv.w;
    __syncthreads();
    #pragma unroll
    for (int kk=0; kk<16; ++kk){
      float4 a4 = *(const float4*)&As[kk][ty*4];
      float4 b4 = *(const float4*)&Bs[kk][tx*4];
      float a_[4] = {a4.x,a4.y,a4.z,a4.w};
      float b_[4] = {b4.x,b4.y,b4.z,b4.w};
      #pragma unroll
      for (int i=0;i<4;i++)
        #pragma unroll
        for (int j=0;j<4;j++) acc[i][j] += a_[i]*b_[j];
    }
  }
  #pragma unroll
  for (int i=0;i<4;i++){
    const int r = row0 + ty*4 + i;
    if (r >= n) continue;
    #pragma unroll
    for (int j=0;j<4;j++){
      const int cc = (col0&255) + tx*4 + j;
      float v = acc[i][j] + bsel[cc];
      u16 bvv = f2bf(v);
      if (sel==3) dsel[(size_t)r*256 + cc] = bvv;
      else { int hh = cc>>6, dd = cc&63; dsel[(((size_t)hh*n + r)<<6) + dd] = bvv; }
    }
  }
}

// ---------------- K2: global max of key data_dash per head ----------------
__global__ __launch_bounds__(256) void k_kmax(
    const u16* __restrict__ K, const float* __restrict__ proj,
    u32* __restrict__ kmaxg, int n)
{
  __shared__ float As[64][68];
  __shared__ float Bs[64][68];
  __shared__ float red[256];
  const int tid = threadIdx.x;
  const int h = blockIdx.y;
  const int node0 = blockIdx.x*64;
  const int tx = tid&15, ty = tid>>4;
  #pragma unroll
  for (int q=0;q<2;q++){
    int e8 = tid + q*256;
    int nn = e8>>3, d0 = (e8&7)*8;
    uint4 raw = make_uint4(0,0,0,0);
    if (node0+nn < n) raw = *(const uint4*)(K + (((size_t)h*n + node0+nn)<<6) + d0);
    const u16* p = (const u16*)&raw;
    #pragma unroll
    for (int s=0;s<8;s++) As[d0+s][nn] = bf2f(p[s]);
  }
  float mx = -3.0e38f;
  #pragma unroll 1
  for (int mc=0; mc<5; ++mc){
    __syncthreads();
    #pragma unroll
    for (int q=0;q<4;q++){
      int fl = tid + q*256;
      int ml = fl>>4, dq = (fl&15)*4;
      int m = mc*64 + ml;
      float4 pv = make_float4(0.f,0.f,0.f,0.f);
      if (m < MF) pv = *(const float4*)(proj + (size_t)m*64 + dq);
      Bs[dq+0][ml]=pv.x; Bs[dq+1][ml]=pv.y; Bs[dq+2][ml]=pv.z; Bs[dq+3][ml]=pv.w;
    }
    __syncthreads();
    float acc[4][4] = {};
    #pragma unroll 4
    for (int d=0; d<64; ++d){
      float4 a4 = *(const float4*)&As[d][ty*4];
      float4 b4 = *(const float4*)&Bs[d][tx*4];
      float a_[4] = {a4.x,a4.y,a4.z,a4.w};
      float b_[4] = {b4.x,b4.y,b4.z,b4.w};
      #pragma unroll
      for (int i=0;i<4;i++)
        #pragma unroll
        for (int j=0;j<4;j++) acc[i][j] += a_[i]*b_[j];
    }
    #pragma unroll
    for (int i=0;i<4;i++)
      #pragma unroll
      for (int j=0;j<4;j++){
        int nn = ty*4+i, m = mc*64+tx*4+j;
        if (node0+nn<n && m<MF) mx = fmaxf(mx, acc[i][j]);
      }
  }
  red[tid] = mx; __syncthreads();
  for (int off=128; off; off>>=1){
    if (tid<off) red[tid] = fmaxf(red[tid], red[tid+off]);
    __syncthreads();
  }
  if (tid==0){
    float f = red[0]*DN;
    u32 b = __float_as_uint(f);
    u32 enc = (b & 0x80000000u) ? ~b : (b | 0x80000000u);
    atomicMax(kmaxg + h, enc);
  }
}

// ---------------- K3: per-(head, m-chunk) kp -> k_sum + context partials ----------------
__global__ __launch_bounds__(256) void k_ctx(
    const u16* __restrict__ K, const u16* __restrict__ V,
    const float* __restrict__ proj, const u32* __restrict__ kmaxg,
    float* __restrict__ ctxp, float* __restrict__ ksump, int n)
{
  __shared__ float As[64][68];   // K^T tile: As[d][node]
  __shared__ u16  Vt[64][72];    // V tile:   Vt[node][d] (raw bf16)
  __shared__ float kp_s[64][68]; // kp chunk: kp_s[node][ml]
  __shared__ float Bs[64][68];   // proj^T chunk: Bs[d][ml]
  __shared__ float diag[64];
  const int tid = threadIdx.x;
  const int h = blockIdx.y / 5, mc = blockIdx.y % 5;
  const int bb = blockIdx.x;
  const int tx = tid&15, ty = tid>>4;
  float mxh; { u32 ee = kmaxg[h]; u32 b = (ee & 0x80000000u) ? (ee ^ 0x80000000u) : ~ee; mxh = __uint_as_float(b); }
  // load proj chunk once (constant for this block)
  #pragma unroll
  for (int q=0;q<4;q++){
    int fl = tid + q*256;
    int ml = fl>>4, dq = (fl&15)*4;
    int m = mc*64 + ml;
    float4 pv = make_float4(0.f,0.f,0.f,0.f);
    if (m < MF) pv = *(const float4*)(proj + (size_t)m*64 + dq);
    Bs[dq+0][ml]=pv.x; Bs[dq+1][ml]=pv.y; Bs[dq+2][ml]=pv.z; Bs[dq+3][ml]=pv.w;
  }
  float acc2[16] = {};
  float ksa = 0.f;
  const int ntile = (n+63)>>6;
  #pragma unroll 1
  for (int t = bb; t < ntile; t += NBCTX){
    const int node0 = t*64;
    __syncthreads();
    #pragma unroll
    for (int q=0;q<2;q++){
      int e8 = tid + q*256;
      int nn = e8>>3, d0 = (e8&7)*8;
      uint4 rk = make_uint4(0,0,0,0), rv = make_uint4(0,0,0,0);
      if (node0+nn < n){
        rk = *(const uint4*)(K + (((size_t)h*n + node0+nn)<<6) + d0);
        rv = *(const uint4*)(V + (((size_t)h*n + node0+nn)<<6) + d0);
      }
      const u16* pk = (const u16*)&rk;
      #pragma unroll
      for (int s=0;s<8;s++) As[d0+s][nn] = bf2f(pk[s]);
      *(uint4*)&Vt[nn][d0] = rv;
    }
    __syncthreads();
    if (tid < 64){
      float s = 0.f;
      #pragma unroll 8
      for (int d=0; d<64; ++d){ float v = As[d][tid]; s += v*v; }
      diag[tid] = 0.0625f*s;
    }
    __syncthreads();
    float acc[4][4] = {};
    #pragma unroll 4
    for (int d=0; d<64; ++d){
      float4 a4 = *(const float4*)&As[d][ty*4];
      float4 b4 = *(const float4*)&Bs[d][tx*4];
      float a_[4] = {a4.x,a4.y,a4.z,a4.w};
      float b_[4] = {b4.x,b4.y,b4.z,b4.w};
      #pragma unroll
      for (int i=0;i<4;i++)
        #pragma unroll
        for (int j=0;j<4;j++) acc[i][j] += a_[i]*b_[j];
    }
    #pragma unroll
    for (int i=0;i<4;i++)
      #pragma unroll
      for (int j=0;j<4;j++){
        int nn = ty*4+i, m = mc*64+tx*4+j;
        float kp = 0.f;
        if (m<MF && node0+nn<n) kp = RATIO*(expf(DN*acc[i][j] - diag[nn] - mxh) + EPSRF);
        kp_s[nn][tx*4+j] = kp;
      }
    __syncthreads();
    if (tid < 64 && mc*64+tid < MF){
      float s = 0.f;
      #pragma unroll 8
      for (int nn=0; nn<64; ++nn) s += kp_s[nn][tid];
      ksa += s;
    }
    #pragma unroll 4
    for (int nn=0; nn<64; ++nn){
      float4 a4 = *(const float4*)&kp_s[nn][ty*4];
      ushort4 bv = *(const ushort4*)&Vt[nn][tx*4];
      float b0=bf2f(bv.x), b1=bf2f(bv.y), b2=bf2f(bv.z), b3=bf2f(bv.w);
      acc2[0]+=a4.x*b0; acc2[1]+=a4.x*b1; acc2[2]+=a4.x*b2; acc2[3]+=a4.x*b3;
      acc2[4]+=a4.y*b0; acc2[5]+=a4.y*b1; acc2[6]+=a4.y*b2; acc2[7]+=a4.y*b3;
      acc2[8]+=a4.z*b0; acc2[9]+=a4.z*b1; acc2[10]+=a4.z*b2; acc2[11]+=a4.z*b3;
      acc2[12]+=a4.w*b0; acc2[13]+=a4.w*b1; acc2[14]+=a4.w*b2; acc2[15]+=a4.w*b3;
    }
  }
  #pragma unroll
  for (int i=0;i<4;i++){
    int m = mc*64 + ty*4 + i;
    if (m < MF){
      float* dst = ctxp + ((((size_t)h*NBCTX + bb)*MF + m)<<6) + tx*4;
      #pragma unroll
      for (int j=0;j<4;j++) dst[j] = acc2[i*4+j];
    }
  }
  if (tid < 64){
    int m = mc*64 + tid;
    if (m < MF) ksump[((size_t)h*NBCTX + bb)*MF + m] = ksa;
  }
}

// ---------------- K3b: reduce partials ----------------
__global__ void k_reduce(const float* __restrict__ ctxp, const float* __restrict__ ksump,
                         float* __restrict__ ctx, float* __restrict__ ksum)
{
  const int T1 = NH*MF*64;
  int idx = blockIdx.x*256 + threadIdx.x;
  if (idx < T1){
    int h = idx / (MF*64);
    int r = idx - h*MF*64;
    float s = 0.f;
    for (int b=0; b<NBCTX; ++b) s += ctxp[(((size_t)h*NBCTX + b)*MF)*64 + r];
    ctx[(size_t)h*MF*64 + r] = s;
  } else if (idx < T1 + NH*MF){
    int k = idx - T1;
    int h = k / MF, m = k - h*MF;
    float s = 0.f;
    for (int b=0; b<NBCTX; ++b) s += ksump[((size_t)h*NBCTX + b)*MF + m];
    ksum[(size_t)h*MF + m] = s;
  }
}

// ---------------- K4: query path -> attention output (trans) ----------------
__global__ __launch_bounds__(256) void k_qattn(
    const u16* __restrict__ Q, const float* __restrict__ proj,
    const float* __restrict__ ctx, const float* __restrict__ ksum,
    u16* __restrict__ trans, int n)
{
  __shared__ float As[64][36];     // Q^T tile [d][node], 32 nodes
  __shared__ float Bc[64][68];     // proj^T chunk / ctx chunk
  __shared__ __half qp_s[32][274];
  __shared__ float diag[32];
  __shared__ float mxs[32];
  __shared__ float dinvs[32];
  const int tid = threadIdx.x;
  const int h = blockIdx.y;
  const int node0 = blockIdx.x*32;
  const int tx = tid&15, ty = tid>>4;
  {
    int nn = tid>>3, d0 = (tid&7)*8;
    uint4 raw = make_uint4(0,0,0,0);
    if (node0+nn < n) raw = *(const uint4*)(Q + (((size_t)h*n + node0+nn)<<6) + d0);
    const u16* p = (const u16*)&raw;
    #pragma unroll
    for (int s=0;s<8;s++) As[d0+s][nn] = bf2f(p[s]);
  }
  __syncthreads();
  if (tid < 32){
    float s = 0.f;
    #pragma unroll 8
    for (int d=0; d<64; ++d){ float v = As[d][tid]; s += v*v; }
    diag[tid] = 0.0625f*s;
  }
  #pragma unroll 1
  for (int mc=0; mc<5; ++mc){
    __syncthreads();
    #pragma unroll
    for (int q=0;q<4;q++){
      int fl = tid + q*256;
      int ml = fl>>4, dq = (fl&15)*4;
      int m = mc*64 + ml;
      float4 pv = make_float4(0.f,0.f,0.f,0.f);
      if (m < MF) pv = *(const float4*)(proj + (size_t)m*64 + dq);
      Bc[dq+0][ml]=pv.x; Bc[dq+1][ml]=pv.y; Bc[dq+2][ml]=pv.z; Bc[dq+3][ml]=pv.w;
    }
    __syncthreads();
    float acc[2][4] = {};
    #pragma unroll 4
    for (int d=0; d<64; ++d){
      float2 a2 = *(const float2*)&As[d][ty*2];
      float4 b4 = *(const float4*)&Bc[d][tx*4];
      acc[0][0]+=a2.x*b4.x; acc[0][1]+=a2.x*b4.y; acc[0][2]+=a2.x*b4.z; acc[0][3]+=a2.x*b4.w;
      acc[1][0]+=a2.y*b4.x; acc[1][1]+=a2.y*b4.y; acc[1][2]+=a2.y*b4.z; acc[1][3]+=a2.y*b4.w;
    }
    #pragma unroll
    for (int i=0;i<2;i++)
      #pragma unroll
      for (int j=0;j<4;j++){
        int m = mc*64 + tx*4 + j;
        if (m < MF) qp_s[ty*2+i][m] = __float2half(DN*acc[i][j]);
      }
  }
  __syncthreads();
  const int t8 = tid&7, n8 = tid>>3;
  {
    float mx = -3.0e38f;
    for (int m = t8; m < MF; m += 8) mx = fmaxf(mx, __half2float(qp_s[n8][m]));
    mx = fmaxf(mx, __shfl_xor(mx, 1, 8));
    mx = fmaxf(mx, __shfl_xor(mx, 2, 8));
    mx = fmaxf(mx, __shfl_xor(mx, 4, 8));
    if (t8==0) mxs[n8] = mx;
  }
  __syncthreads();
  for (int idx = tid; idx < 32*MF; idx += 256){
    int nn = idx / MF, m = idx - nn*MF;
    float v = __half2float(qp_s[nn][m]);
    qp_s[nn][m] = __float2half(RATIO*(expf(v - diag[nn] - mxs[nn]) + EPSRF));
  }
  __syncthreads();
  {
    float s = 0.f;
    for (int m = t8; m < MF; m += 8) s += __half2float(qp_s[n8][m]) * ksum[(size_t)h*MF + m];
    s += __shfl_xor(s, 1, 8); s += __shfl_xor(s, 2, 8); s += __shfl_xor(s, 4, 8);
    if (t8==0) dinvs[n8] = 1.f/s;
  }
  float acco[2][4] = {};
  #pragma unroll 1
  for (int mc=0; mc<5; ++mc){
    __syncthreads();
    #pragma unroll
    for (int q=0;q<4;q++){
      int fl = tid + q*256;
      int ml = fl>>4, dq = (fl&15)*4;
      int m = mc*64 + ml;
      float4 cv = make_float4(0.f,0.f,0.f,0.f);
      if (m < MF) cv = *(const float4*)(ctx + (((size_t)h*MF + m)<<6) + dq);
      *(float4*)&Bc[ml][dq] = cv;
    }
    __syncthreads();
    const int cmax = (mc<4)? 64 : (MF-256);
    #pragma unroll 4
    for (int ml=0; ml<cmax; ++ml){
      float a0 = __half2float(qp_s[ty*2+0][mc*64+ml]);
      float a1 = __half2float(qp_s[ty*2+1][mc*64+ml]);
      float4 b4 = *(const float4*)&Bc[ml][tx*4];
      acco[0][0]+=a0*b4.x; acco[0][1]+=a0*b4.y; acco[0][2]+=a0*b4.z; acco[0][3]+=a0*b4.w;
      acco[1][0]+=a1*b4.x; acco[1][1]+=a1*b4.y; acco[1][2]+=a1*b4.z; acco[1][3]+=a1*b4.w;
    }
  }
  #pragma unroll
  for (int i=0;i<2;i++){
    int ng = node0 + ty*2 + i;
    if (ng < n){
      float dv = dinvs[ty*2+i];
      ushort4 o;
      o.x = f2bf(acco[i][0]*dv); o.y = f2bf(acco[i][1]*dv);
      o.z = f2bf(acco[i][2]*dv); o.w = f2bf(acco[i][3]*dv);
      *(ushort4*)(trans + (size_t)ng*256 + h*64 + tx*4) = o;
    }
  }
}

// ---------------- small transpose for lin2_w ----------------
__global__ void k_tr_l2(const float* __restrict__ w, float* __restrict__ wT){
  int i = blockIdx.x*256 + threadIdx.x;
  if (i < 32*512){ int o = i>>9, f = i&511; wT[f*32 + o] = w[i]; }
}

// ---------------- K5: cat -> elu -> lin2 -> elu ----------------
__global__ __launch_bounds__(256) void k_gnn2(
    const u16* __restrict__ G1, const u16* __restrict__ trans,
    const float* __restrict__ l2wT, const float* __restrict__ l2b,
    float* __restrict__ out, int n)
{
  __shared__ u16 cat_s[32][516];
  const int tid = threadIdx.x;
  const int node0 = blockIdx.x*32;
  for (int e = tid; e < 32*512; e += 256){
    int nn = e>>9, f = e&511;
    int ng = node0+nn; float v = 0.f;
    if (ng<n) v = bf2f(f<256 ? G1[(size_t)ng*256+f] : trans[(size_t)ng*256+f-256]);
    cat_s[nn][f] = f2bf(eluf(v));
  }
  __syncthreads();
  const int o = tid&31, half = tid>>5;
  float bb = l2b[o];
  float acc[4] = {bb,bb,bb,bb};
  for (int f=0; f<512; ++f){
    float w = l2wT[f*32 + o];
    #pragma unroll
    for (int i=0;i<4;i++) acc[i] += bf2f(cat_s[half + i*8][f]) * w;
  }
  #pragma unroll
  for (int i=0;i<4;i++){
    int ng = node0 + half + i*8;
    if (ng<n) out[(size_t)ng*32 + o] = eluf(acc[i]);
  }
}

// ---------------- edge layout detect (int32 vs int64) ----------------
__global__ void k_edgemode(const int* __restrict__ ei, int* __restrict__ mode){
  __shared__ int any;
  if (threadIdx.x==0) any = 0;
  __syncthreads();
  if (ei[threadIdx.x*2+1] != 0) any = 1;
  __syncthreads();
  if (threadIdx.x==0) *mode = any;   // 1 = int32 layout, 0 = int64 layout
}
__device__ __forceinline__ int edge_at(const int* ei, int mode, size_t idx){
  if (mode) return ei[idx];
  return (int)((const long long*)ei)[idx];
}

// ---------------- CSR build ----------------
__global__ void k_hist(const int* __restrict__ ei, const int* __restrict__ mode,
                       u32* __restrict__ deg, int e){
  const int md = *mode;
  for (size_t i = (size_t)blockIdx.x*blockDim.x + threadIdx.x; i < (size_t)e; i += (size_t)gridDim.x*blockDim.x)
    atomicAdd(&deg[edge_at(ei, md, (size_t)e + i)], 1u);
}
__global__ void k_dis(const u32* __restrict__ deg, float* __restrict__ dis, int n){
  int i = blockIdx.x*256 + threadIdx.x;
  if (i<n) dis[i] = rsqrtf((float)(deg[i] + 1u));
}
__global__ __launch_bounds__(1024) void k_scan(const u32* __restrict__ deg, u32* __restrict__ rowp, int n){
  __shared__ u32 sm[1024];
  __shared__ u32 carry;
  if (threadIdx.x==0){ carry = 0u; rowp[0] = 0u; }
  __syncthreads();
  for (int base=0; base<n; base+=1024){
    int i = base + (int)threadIdx.x;
    u32 v = (i<n)? deg[i] : 0u;
    sm[threadIdx.x] = v; __syncthreads();
    for (int off=1; off<1024; off<<=1){
      u32 t = (threadIdx.x>=(u32)off)? sm[threadIdx.x-off] : 0u;
      __syncthreads();
      sm[threadIdx.x] += t;
      __syncthreads();
    }
    if (i<n) rowp[i+1] = carry + sm[threadIdx.x];
    __syncthreads();
    if (threadIdx.x==0) carry += sm[1023];
    __syncthreads();
  }
}
__global__ void k_copy(const u32* __restrict__ a, u32* __restrict__ b, int n){
  int i = blockIdx.x*256 + threadIdx.x; if (i<n) b[i]=a[i];
}
__global__ void k_fill(const int* __restrict__ ei, const int* __restrict__ mode,
                       const float* __restrict__ dis,
                       u32* __restrict__ cur, int* __restrict__ col, float* __restrict__ wgt, int e){
  const int md = *mode;
  for (size_t i = (size_t)blockIdx.x*blockDim.x + threadIdx.x; i < (size_t)e; i += (size_t)gridDim.x*blockDim.x){
    int s = edge_at(ei, md, i);
    int t = edge_at(ei, md, (size_t)e + i);
    u32 pos = atomicAdd(&cur[t], 1u);
    col[pos] = s;
    wgt[pos] = dis[s]*dis[t];
  }
}

// ---------------- APPNP iteration (gather form) ----------------
__global__ __launch_bounds__(256) void k_appnp(
    const float* __restrict__ xin, const float* __restrict__ hbuf,
    float* __restrict__ xout, const u32* __restrict__ rowp,
    const int* __restrict__ col, const float* __restrict__ wgt,
    const float* __restrict__ dis, int n)
{
  const int g = threadIdx.x>>5, j = threadIdx.x&31;
  const int node = blockIdx.x*8 + g;
  if (node >= n) return;
  float d0 = dis[node];
  float acc = d0*d0*xin[((size_t)node<<5) + j];
  u32 r0 = rowp[node], r1 = rowp[node+1];
  for (u32 k = r0; k < r1; ++k)
    acc += wgt[k] * xin[((size_t)col[k]<<5) + j];
  xout[((size_t)node<<5)+j] = 0.9f*acc + 0.1f*hbuf[((size_t)node<<5)+j];
}

// ---------------- log_softmax + raw ----------------
__global__ __launch_bounds__(256) void k_lsm(const float* __restrict__ xin, float* __restrict__ out, int n){
  const int g = threadIdx.x>>5, j = threadIdx.x&31;
  const int node = blockIdx.x*8 + g;
  if (node>=n) return;
  float v = xin[((size_t)node<<5)+j];
  float m = v;
  #pragma unroll
  for (int o=16;o;o>>=1) m = fmaxf(m, __shfl_xor(m, o, 32));
  float s = expf(v - m);
  #pragma unroll
  for (int o=16;o;o>>=1) s += __shfl_xor(s, o, 32);
  out[((size_t)node<<5)+j] = v - m - logf(s);
  out[(size_t)n*32 + ((size_t)node<<5)+j] = v;
}

extern "C" void kernel_launch(void* const* d_in, const int* in_sizes, int n_in,
                              void* d_out, int out_size, void* d_ws, size_t ws_size,
                              hipStream_t stream)
{
  const float* x   = (const float*)d_in[0];
  const int*   ei  = (const int*)  d_in[1];
  const float* l1w = (const float*)d_in[2];
  const float* l1b = (const float*)d_in[3];
  const float* l2w = (const float*)d_in[4];
  const float* l2b = (const float*)d_in[5];
  const float* qw  = (const float*)d_in[6];
  const float* qb  = (const float*)d_in[7];
  const float* kw  = (const float*)d_in[8];
  const float* kb  = (const float*)d_in[9];
  const float* vw  = (const float*)d_in[10];
  const float* vb  = (const float*)d_in[11];
  const float* proj= (const float*)d_in[12];
  const int n = in_sizes[0] / 256;
  const int e = in_sizes[1] / 2;

  char* ws = (char*)d_ws;
  auto au = [](size_t v){ return (v + 255) & ~(size_t)255; };
  const size_t bQ = (size_t)n * 512;                 // bf16 [4][n][64]
  const size_t oQ = 0;
  const size_t oK = au(oQ + bQ);
  const size_t oV = au(oK + bQ);
  const size_t oG1 = au(oV + bQ);
  const size_t oCtxp = au(oG1 + bQ);
  const size_t bCtxp = (size_t)NH*NBCTX*MF*64*4;
  const size_t oKsump = au(oCtxp + bCtxp);
  const size_t bKsump = (size_t)NH*NBCTX*MF*4;
  const size_t oCtx = au(oKsump + bKsump);
  const size_t oKsum = au(oCtx + (size_t)NH*MF*64*4);
  const size_t oKmax = au(oKsum + (size_t)NH*MF*4);
  const size_t oMode = oKmax + 64;
  const size_t oL2wT = au(oKmax + 256);
  // aliases (Q region dead after k_qattn; K region dead after k_ctx; V dead after k_ctx)
  const size_t oTrans = oK;
  const size_t oG2 = oQ;
  const size_t oXA = au(oG2 + (size_t)n*32*4);
  const size_t oXB = au(oXA + (size_t)n*32*4);
  const size_t oDeg = au(oXB + (size_t)n*32*4);
  const size_t oDis = au(oDeg + (size_t)n*4);
  const size_t oRowp= au(oDis + (size_t)n*4);
  const size_t oCur = au(oRowp + (size_t)(n+1)*4);
  const size_t oCol = oV;
  const size_t oWgt = au(oCol + (size_t)e*4);
  (void)oCur; (void)oWgt; (void)ws_size; (void)n_in; (void)out_size;

  u16* Q  = (u16*)(ws + oQ);
  u16* Kb = (u16*)(ws + oK);
  u16* Vb = (u16*)(ws + oV);
  u16* G1 = (u16*)(ws + oG1);
  float* ctxp = (float*)(ws + oCtxp);
  float* ksump= (float*)(ws + oKsump);
  float* ctx  = (float*)(ws + oCtx);
  float* ksum = (float*)(ws + oKsum);
  u32*  kmax  = (u32*)(ws + oKmax);
  int*  mode  = (int*)(ws + oMode);
  float* l2wT = (float*)(ws + oL2wT);
  u16* trans  = (u16*)(ws + oTrans);
  float* G2   = (float*)(ws + oG2);
  float* xA   = (float*)(ws + oXA);
  float* xB   = (float*)(ws + oXB);
  u32* deg    = (u32*)(ws + oDeg);
  float* dis  = (float*)(ws + oDis);
  u32* rowp   = (u32*)(ws + oRowp);
  u32* cur    = (u32*)(ws + oCur);
  int* col    = (int*)(ws + oCol);
  float* wgt  = (float*)(ws + oWgt);

  const int nt64 = (n+63)/64, nt32 = (n+31)/32;

  hipMemsetAsync(ws + oKmax, 0, 16, stream);
  k_proj<<<dim3(nt64,16),256,0,stream>>>(x,qw,kw,vw,l1w,qb,kb,vb,l1b,Q,Kb,Vb,G1,n);
  k_kmax<<<dim3(nt64,4),256,0,stream>>>(Kb,proj,kmax,n);
  k_ctx<<<dim3(NBCTX,20),256,0,stream>>>(Kb,Vb,proj,kmax,ctxp,ksump,n);
  {
    int tot = NH*MF*64 + NH*MF;
    k_reduce<<<(tot+255)/256,256,0,stream>>>(ctxp,ksump,ctx,ksum);
  }
  k_qattn<<<dim3(nt32,4),256,0,stream>>>(Q,proj,ctx,ksum,trans,n);
  k_tr_l2<<<64,256,0,stream>>>(l2w,l2wT);
  k_gnn2<<<nt32,256,0,stream>>>(G1,trans,l2wT,l2b,G2,n);
  // ---- APPNP ----
  k_edgemode<<<1,256,0,stream>>>(ei,mode);
  hipMemsetAsync(ws + oDeg, 0, (size_t)n*4, stream);
  k_hist<<<2048,256,0,stream>>>(ei,mode,deg,e);
  k_dis<<<(n+255)/256,256,0,stream>>>(deg,dis,n);
  k_scan<<<1,1024,0,stream>>>(deg,rowp,n);
  k_copy<<<(n+255)/256,256,0,stream>>>(rowp,cur,n);
  k_fill<<<2048,256,0,stream>>>(ei,mode,dis,cur,col,wgt,e);
  const float* curx = G2;
  float* bufs[2] = {xA, xB};
  for (int it=0; it<10; ++it){
    float* nxt = bufs[it&1];
    k_appnp<<<(n+7)/8,256,0,stream>>>(curx,G2,nxt,rowp,col,wgt,dis,n);
    curx = nxt;
  }
  k_lsm<<<(n+7)/8,256,0,stream>>>(curx,(float*)d_out,n);
}